// Round 3
// baseline (193.132 us; speedup 1.0000x reference)
//
#include <hip/hip_runtime.h>
#include <hip/hip_cooperative_groups.h>

namespace cg = cooperative_groups;

// NT-Xent positive-pair loss:
//   cos_k = dot(z_i[k], z_j[k]) / max(||z_i[k]|| * ||z_j[k]||, EPS)
//   loss  = sum_k (cos_k / T)^2 * 2 / N^2,  N = 2B
// B = 16384, D = 512, T = 0.5, EPS = 1e-8.
//
// Single cooperative kernel: 1024 blocks x 256 thr, 16 lanes per row
// (4 rows/wave, 16 rows/block -> exactly 16384 rows). Each block stores one
// partial to d_ws, grid.sync(), then block 0 reduces 1024 partials -> out.
// Co-residency: 16 waves/CU (4 blocks/CU on 256 CUs), well under 32.

constexpr int   D_DIM  = 512;
constexpr float EPS    = 1e-8f;
constexpr float INV_TEMP = 2.0f;                          // 1 / 0.5
constexpr float SCALE    = 2.0f / (32768.0f * 32768.0f);  // 2 / N^2

__global__ __launch_bounds__(256) void ntxent_fused_kernel(
    const float* __restrict__ zi,
    const float* __restrict__ zj,
    float* __restrict__ partials,
    float* __restrict__ out)
{
    const int lane        = threadIdx.x & 63;
    const int wave_in_blk = threadIdx.x >> 6;
    const int g    = lane & 15;   // lane within 16-lane row-group
    const int grp  = lane >> 4;   // 0..3: which row this group handles
    const int wave = blockIdx.x * 4 + wave_in_blk;   // 0..4095
    const int row  = wave * 4 + grp;                 // 0..16383, one pass

    const float4* a4 = (const float4*)(zi + (size_t)row * D_DIM);
    const float4* b4 = (const float4*)(zj + (size_t)row * D_DIM);

    float dot = 0.0f, na = 0.0f, nb = 0.0f;
    // 512 floats / 16 lanes = 8 float4 per lane; each load instruction covers
    // 4 contiguous 256B chunks in 4 adjacent rows (full cache lines).
    #pragma unroll
    for (int k = 0; k < 8; ++k) {
        float4 a = a4[g + 16 * k];
        float4 b = b4[g + 16 * k];
        dot += a.x * b.x + a.y * b.y + a.z * b.z + a.w * b.w;
        na  += a.x * a.x + a.y * a.y + a.z * a.z + a.w * a.w;
        nb  += b.x * b.x + b.y * b.y + b.z * b.z + b.w * b.w;
    }

    // Reduce across the 16 lanes of the row-group (4 xor steps).
    #pragma unroll
    for (int m = 8; m >= 1; m >>= 1) {
        dot += __shfl_xor(dot, m, 64);
        na  += __shfl_xor(na,  m, 64);
        nb  += __shfl_xor(nb,  m, 64);
    }

    float acc = 0.0f;
    if (g == 0) {   // 4 group-leader lanes per wave, one row each
        float norm_prod = sqrtf(na) * sqrtf(nb);
        float cosv = dot / fmaxf(norm_prod, EPS);
        float pos  = cosv * INV_TEMP;
        acc = pos * pos;
    }
    // Sum the 4 group results across the wave (lanes 0,16,32,48 hold values).
    acc += __shfl_xor(acc, 16, 64);
    acc += __shfl_xor(acc, 32, 64);

    __shared__ float s[4];
    if (lane == 0) s[wave_in_blk] = acc;
    __syncthreads();
    if (threadIdx.x == 0)
        partials[blockIdx.x] = (s[0] + s[1]) + (s[2] + s[3]);

    cg::this_grid().sync();   // device-scope fence + grid barrier

    if (blockIdx.x == 0) {
        // 1024 partials, 256 threads -> 4 each.
        float v = partials[threadIdx.x]
                + partials[threadIdx.x + 256]
                + partials[threadIdx.x + 512]
                + partials[threadIdx.x + 768];
        #pragma unroll
        for (int m = 32; m >= 1; m >>= 1)
            v += __shfl_xor(v, m, 64);

        if (lane == 0) s[wave_in_blk] = v;
        __syncthreads();
        if (threadIdx.x == 0)
            out[0] = ((s[0] + s[1]) + (s[2] + s[3])) * SCALE;
    }
}

extern "C" void kernel_launch(void* const* d_in, const int* in_sizes, int n_in,
                              void* d_out, int out_size, void* d_ws, size_t ws_size,
                              hipStream_t stream)
{
    const float* zi = (const float*)d_in[0];
    const float* zj = (const float*)d_in[1];
    float* partials = (float*)d_ws;   // 1024 floats = 4 KiB of scratch
    float* out = (float*)d_out;

    void* args[] = { (void*)&zi, (void*)&zj, (void*)&partials, (void*)&out };
    hipLaunchCooperativeKernel((void*)ntxent_fused_kernel,
                               dim3(1024), dim3(256), args, 0, stream);
}

// Round 4
// 91.079 us; speedup vs baseline: 2.1205x; 2.1205x over previous
//
#include <hip/hip_runtime.h>

// NT-Xent positive-pair loss:
//   cos_k = dot(z_i[k], z_j[k]) / max(||z_i[k]|| * ||z_j[k]||, EPS)
//   loss  = sum_k (cos_k / T)^2 * 2 / N^2,  N = 2B
// B = 16384, D = 512, T = 0.5, EPS = 1e-8.
//
// Two kernels (cooperative grid.sync measured at ~90us on ROCm - rejected).
// Kernel 1: 2048 blocks x 256 thr = 32 waves/CU (100% occupancy; inputs are
// L3-resident on timed replays, so this is Infinity-Cache-latency/BW bound
// and wants maximum loads in flight). 32 lanes per row, 2 rows/wave,
// 8 rows/block -> exactly 16384 rows. One partial store per block.
// Kernel 2: one 64-lane wave reduces 2048 partials, writes scaled scalar.

constexpr int   D_DIM  = 512;
constexpr float EPS    = 1e-8f;
constexpr float INV_TEMP = 2.0f;                          // 1 / 0.5
constexpr float SCALE    = 2.0f / (32768.0f * 32768.0f);  // 2 / N^2

__global__ __launch_bounds__(256) void ntxent_partial_kernel(
    const float* __restrict__ zi,
    const float* __restrict__ zj,
    float* __restrict__ partials)
{
    const int lane        = threadIdx.x & 63;
    const int wave_in_blk = threadIdx.x >> 6;
    const int g    = lane & 31;   // lane within 32-lane row-group
    const int grp  = lane >> 5;   // 0..1: which row this group handles
    const int wave = blockIdx.x * 4 + wave_in_blk;   // 0..8191
    const int row  = wave * 2 + grp;                 // 0..16383, one pass

    const float4* a4 = (const float4*)(zi + (size_t)row * D_DIM);
    const float4* b4 = (const float4*)(zj + (size_t)row * D_DIM);

    float dot = 0.0f, na = 0.0f, nb = 0.0f;
    // 512 floats / 32 lanes = 4 float4 per lane; each load instruction covers
    // two contiguous 512B spans in two adjacent rows (full cache lines).
    #pragma unroll
    for (int k = 0; k < 4; ++k) {
        float4 a = a4[g + 32 * k];
        float4 b = b4[g + 32 * k];
        dot += a.x * b.x + a.y * b.y + a.z * b.z + a.w * b.w;
        na  += a.x * a.x + a.y * a.y + a.z * a.z + a.w * a.w;
        nb  += b.x * b.x + b.y * b.y + b.z * b.z + b.w * b.w;
    }

    // Reduce across the 32 lanes of the row-group (5 xor steps).
    #pragma unroll
    for (int m = 16; m >= 1; m >>= 1) {
        dot += __shfl_xor(dot, m, 64);
        na  += __shfl_xor(na,  m, 64);
        nb  += __shfl_xor(nb,  m, 64);
    }

    float acc = 0.0f;
    if (g == 0) {   // lanes 0 and 32 hold one row's result each
        float norm_prod = sqrtf(na) * sqrtf(nb);
        float cosv = dot / fmaxf(norm_prod, EPS);
        float pos  = cosv * INV_TEMP;
        acc = pos * pos;
    }
    acc += __shfl_xor(acc, 32, 64);   // combine the wave's two rows

    __shared__ float s[4];
    if (lane == 0) s[wave_in_blk] = acc;
    __syncthreads();
    if (threadIdx.x == 0)
        partials[blockIdx.x] = (s[0] + s[1]) + (s[2] + s[3]);
}

__global__ __launch_bounds__(64) void ntxent_finalize_kernel(
    const float* __restrict__ partials,
    float* __restrict__ out)
{
    // 2048 partials = 512 float4; 64 lanes x 8 float4 each, coalesced.
    const float4* p4 = (const float4*)partials;
    const int lane = threadIdx.x;
    float v = 0.0f;
    #pragma unroll
    for (int k = 0; k < 8; ++k) {
        float4 p = p4[lane + 64 * k];
        v += (p.x + p.y) + (p.z + p.w);
    }
    #pragma unroll
    for (int m = 32; m >= 1; m >>= 1)
        v += __shfl_xor(v, m, 64);
    if (lane == 0)
        out[0] = v * SCALE;
}

extern "C" void kernel_launch(void* const* d_in, const int* in_sizes, int n_in,
                              void* d_out, int out_size, void* d_ws, size_t ws_size,
                              hipStream_t stream)
{
    const float* zi = (const float*)d_in[0];
    const float* zj = (const float*)d_in[1];
    float* partials = (float*)d_ws;   // 2048 floats = 8 KiB of scratch
    float* out = (float*)d_out;

    ntxent_partial_kernel<<<2048, 256, 0, stream>>>(zi, zj, partials);
    ntxent_finalize_kernel<<<1, 64, 0, stream>>>(partials, out);
}